// Round 1
// baseline (3177.408 us; speedup 1.0000x reference)
//
#include <hip/hip_runtime.h>
#include <stdint.h>

#define D_DIM  1024
#define NROWS  4096
#define NSEG   8
#define QN     4000
#define NCODES 32000
#define VOFF   2
#define BM     128
#define BN     128
#define BK     16

// ws layout (bytes): c2[32000]f32 | x2[4096]f32 | cells[32768]u64 | part[4096]f64
#define C2_OFF    0
#define X2_OFF    131072
#define CELLS_OFF 163840
#define PART_OFF  458752

__device__ inline unsigned long long shfl_xor_u64_w16(unsigned long long v, int m) {
  unsigned lo = (unsigned)(v & 0xffffffffULL);
  unsigned hi = (unsigned)(v >> 32);
  lo = (unsigned)__shfl_xor((int)lo, m, 16);
  hi = (unsigned)__shfl_xor((int)hi, m, 16);
  return ((unsigned long long)hi << 32) | lo;
}

// One block per row: b < 32000 -> c2 of code row, else x2 of input row.
__global__ __launch_bounds__(256) void rowsq_kernel(const float* __restrict__ emb,
                                                    const float* __restrict__ x,
                                                    float* __restrict__ c2,
                                                    float* __restrict__ x2) {
  int b = blockIdx.x;
  int t = threadIdx.x;
  const float* src = (b < NCODES) ? (emb + (size_t)(VOFF + b) * D_DIM)
                                  : (x + (size_t)(b - NCODES) * D_DIM);
  float4 v = ((const float4*)src)[t];
  float s = v.x * v.x + v.y * v.y + v.z * v.z + v.w * v.w;
  for (int off = 32; off > 0; off >>= 1) s += __shfl_down(s, off, 64);
  __shared__ float red[4];
  if ((t & 63) == 0) red[t >> 6] = s;
  __syncthreads();
  if (t == 0) {
    float tot = red[0] + red[1] + red[2] + red[3];
    if (b < NCODES) c2[b] = tot; else x2[b - NCODES] = tot;
  }
}

// fp32 GEMM tile (128x128, BK=16, 8x8 per thread) + fused per-(row,seg) argmin.
__global__ __launch_bounds__(256) void score_kernel(const float* __restrict__ x,
                                                    const float* __restrict__ emb,
                                                    const float* __restrict__ c2,
                                                    const float* __restrict__ x2,
                                                    unsigned long long* __restrict__ cells) {
  __shared__ float lds_a[BK][BM];
  __shared__ float lds_b[BK][BN];
  int tid = threadIdx.x;
  int m0 = blockIdx.x * BM;          // row tile
  int q0 = blockIdx.y * BN;          // q tile within segment (last tile partial)
  int seg = blockIdx.z;
  int tx = tid & 15, ty = tid >> 4;

  float acc[8][8];
#pragma unroll
  for (int i = 0; i < 8; i++)
#pragma unroll
    for (int j = 0; j < 8; j++) acc[i][j] = 0.0f;

  int sr = tid >> 2;                 // 0..63
  int sk = (tid & 3) << 2;           // 0,4,8,12
  int qa0 = q0 + sr;       if (qa0 > QN - 1) qa0 = QN - 1;
  int qa1 = q0 + sr + 64;  if (qa1 > QN - 1) qa1 = QN - 1;
  const float* aptr0 = x + (size_t)(m0 + sr) * D_DIM + sk;
  const float* aptr1 = x + (size_t)(m0 + sr + 64) * D_DIM + sk;
  const float* bptr0 = emb + (size_t)(VOFF + seg * QN + qa0) * D_DIM + sk;
  const float* bptr1 = emb + (size_t)(VOFF + seg * QN + qa1) * D_DIM + sk;

  for (int kt = 0; kt < D_DIM; kt += BK) {
    float4 a0 = *(const float4*)(aptr0 + kt);
    float4 a1 = *(const float4*)(aptr1 + kt);
    float4 b0 = *(const float4*)(bptr0 + kt);
    float4 b1 = *(const float4*)(bptr1 + kt);
    __syncthreads();
    lds_a[sk + 0][sr] = a0.x; lds_a[sk + 1][sr] = a0.y;
    lds_a[sk + 2][sr] = a0.z; lds_a[sk + 3][sr] = a0.w;
    lds_a[sk + 0][sr + 64] = a1.x; lds_a[sk + 1][sr + 64] = a1.y;
    lds_a[sk + 2][sr + 64] = a1.z; lds_a[sk + 3][sr + 64] = a1.w;
    lds_b[sk + 0][sr] = b0.x; lds_b[sk + 1][sr] = b0.y;
    lds_b[sk + 2][sr] = b0.z; lds_b[sk + 3][sr] = b0.w;
    lds_b[sk + 0][sr + 64] = b1.x; lds_b[sk + 1][sr + 64] = b1.y;
    lds_b[sk + 2][sr + 64] = b1.z; lds_b[sk + 3][sr + 64] = b1.w;
    __syncthreads();
#pragma unroll
    for (int k = 0; k < BK; k++) {
      float4 av0 = *(const float4*)&lds_a[k][ty * 4];
      float4 av1 = *(const float4*)&lds_a[k][ty * 4 + 64];
      float4 bv0 = *(const float4*)&lds_b[k][tx * 4];
      float4 bv1 = *(const float4*)&lds_b[k][tx * 4 + 64];
      float av[8] = {av0.x, av0.y, av0.z, av0.w, av1.x, av1.y, av1.z, av1.w};
      float bv[8] = {bv0.x, bv0.y, bv0.z, bv0.w, bv1.x, bv1.y, bv1.z, bv1.w};
#pragma unroll
      for (int i = 0; i < 8; i++)
#pragma unroll
        for (int j = 0; j < 8; j++) acc[i][j] += av[i] * bv[j];
    }
  }

  // Epilogue: dist = (x2 + c2) - 2*S  (numpy formula order); argmin w/ tie->smaller q
  float c2v[8];
  unsigned negq[8];
  bool val[8];
#pragma unroll
  for (int j = 0; j < 8; j++) {
    int q = q0 + tx * 4 + (j & 3) + ((j >> 2) << 6);
    val[j] = (q < QN);
    c2v[j] = c2[seg * QN + (val[j] ? q : 0)];
    negq[j] = ~(unsigned)q;
  }
#pragma unroll
  for (int i = 0; i < 8; i++) {
    int row = m0 + ty * 4 + (i & 3) + ((i >> 2) << 6);
    float x2r = x2[row];
    unsigned long long best = 0ULL;
#pragma unroll
    for (int j = 0; j < 8; j++) {
      if (!val[j]) continue;
      float dist = (x2r + c2v[j]) - 2.0f * acc[i][j];
      unsigned u = __float_as_uint(dist);
      unsigned asc = (u & 0x80000000u) ? ~u : (u | 0x80000000u);
      unsigned key = ~asc;  // smaller dist -> larger key
      unsigned long long p = ((unsigned long long)key << 32) | (unsigned long long)negq[j];
      if (p > best) best = p;
    }
#pragma unroll
    for (int m = 1; m < 16; m <<= 1) {
      unsigned long long o = shfl_xor_u64_w16(best, m);
      if (o > best) best = o;
    }
    if (tx == 0) atomicMax(&cells[(size_t)row * NSEG + seg], best);
  }
}

// One block per row: gather 8 selected codes, mean, write quantized_st, mse partial.
__global__ __launch_bounds__(256) void gather_kernel(const float* __restrict__ x,
                                                     const float* __restrict__ emb,
                                                     const float* __restrict__ mask,
                                                     const unsigned long long* __restrict__ cells,
                                                     float* __restrict__ out,
                                                     double* __restrict__ part) {
  int n = blockIdx.x;
  int t = threadIdx.x;
  __shared__ int qsel[NSEG];
  if (t < NSEG) qsel[t] = (int)(~(unsigned)(cells[(size_t)n * NSEG + t] & 0xffffffffULL));
  __syncthreads();
  float4 xv = ((const float4*)(x + (size_t)n * D_DIM))[t];
  float ax = 0.f, ay = 0.f, az = 0.f, aw = 0.f;
#pragma unroll
  for (int s = 0; s < NSEG; s++) {
    float4 cv = ((const float4*)(emb + (size_t)(VOFF + s * QN + qsel[s]) * D_DIM))[t];
    ax += cv.x; ay += cv.y; az += cv.z; aw += cv.w;
  }
  float qx = ax * 0.125f, qy = ay * 0.125f, qz = az * 0.125f, qw = aw * 0.125f;
  float4 o4;
  o4.x = xv.x + (qx - xv.x);
  o4.y = xv.y + (qy - xv.y);
  o4.z = xv.z + (qz - xv.z);
  o4.w = xv.w + (qw - xv.w);
  ((float4*)(out + (size_t)n * D_DIM))[t] = o4;
  float mk = mask[n];
  float dx = qx * mk - xv.x * mk;
  float dy = qy * mk - xv.y * mk;
  float dz = qz * mk - xv.z * mk;
  float dw = qw * mk - xv.w * mk;
  float ss = dx * dx + dy * dy + dz * dz + dw * dw;
  double sd = (double)ss;
  for (int off = 32; off > 0; off >>= 1) sd += __shfl_down(sd, off, 64);
  __shared__ double red[4];
  if ((t & 63) == 0) red[t >> 6] = sd;
  __syncthreads();
  if (t == 0) part[n] = red[0] + red[1] + red[2] + red[3];
}

__global__ __launch_bounds__(256) void finalize_kernel(const double* __restrict__ part,
                                                       float* __restrict__ loss_out) {
  int t = threadIdx.x;
  double s = 0.0;
  for (int i = t; i < NROWS; i += 256) s += part[i];
  for (int off = 32; off > 0; off >>= 1) s += __shfl_down(s, off, 64);
  __shared__ double red[4];
  if ((t & 63) == 0) red[t >> 6] = s;
  __syncthreads();
  if (t == 0) {
    double tot = red[0] + red[1] + red[2] + red[3];
    float m = (float)(tot / (double)((size_t)NROWS * D_DIM));
    loss_out[0] = m + 0.25f * m;
  }
}

extern "C" void kernel_launch(void* const* d_in, const int* in_sizes, int n_in,
                              void* d_out, int out_size, void* d_ws, size_t ws_size,
                              hipStream_t stream) {
  const float* x    = (const float*)d_in[0];  // inputs_embeds [4,1024,1024]
  const float* emb  = (const float*)d_in[1];  // emb_weight [32002,1024]
  const float* mask = (const float*)d_in[2];  // attention_mask [4,1024]
  (void)in_sizes; (void)n_in; (void)ws_size;

  char* ws = (char*)d_ws;
  float* c2 = (float*)(ws + C2_OFF);
  float* x2 = (float*)(ws + X2_OFF);
  unsigned long long* cells = (unsigned long long*)(ws + CELLS_OFF);
  double* part = (double*)(ws + PART_OFF);
  float* out = (float*)d_out;

  hipMemsetAsync(cells, 0, (size_t)NROWS * NSEG * sizeof(unsigned long long), stream);
  rowsq_kernel<<<dim3(NCODES + NROWS), 256, 0, stream>>>(emb, x, c2, x2);
  score_kernel<<<dim3(NROWS / BM, (QN + BN - 1) / BN, NSEG), 256, 0, stream>>>(x, emb, c2, x2, cells);
  gather_kernel<<<dim3(NROWS), 256, 0, stream>>>(x, emb, mask, cells, out, part);
  finalize_kernel<<<dim3(1), 256, 0, stream>>>(part, out + (size_t)NROWS * D_DIM);
}

// Round 3
// 1342.296 us; speedup vs baseline: 2.3671x; 2.3671x over previous
//
#include <hip/hip_runtime.h>
#include <stdint.h>

#define D_DIM  1024
#define NROWS  4096
#define NSEG   8
#define QN     4000
#define NCODES 32000
#define VOFF   2

#define BM 128
#define BN 128
#define BK 32
#define LDK 40           // padded k-stride in shorts (80B rows: 2-way bank alias = free)

#define MARGIN_F 4.0f
#define MARGIN_Q 66      // 4.0*16 + quantization slack
#define CAP      262144u

// ws layout (bytes)
#define C2_OFF     0u
#define X2_OFF     131072u
#define CELLS_OFF  147456u
#define MINF_OFF   409600u
#define CNT_OFF    540672u
#define PART_OFF   540928u
#define LIST_OFF   573696u
#define STASH_OFF  1622272u
#define WS_NEED_A  10010880u

typedef short bf16x8 __attribute__((ext_vector_type(8)));
typedef float f32x4  __attribute__((ext_vector_type(4)));

__device__ inline short f2bs(float f) {          // fp32 -> bf16 RNE, finite inputs
  unsigned u = __float_as_uint(f);
  unsigned r = (u + 0x7FFFu + ((u >> 16) & 1u)) >> 16;
  return (short)r;
}
__device__ inline unsigned shflx_u32(unsigned v, int m) {
  return (unsigned)__shfl_xor((int)v, m, 64);
}

// ---------------- rowsq: c2 / x2 ----------------
__global__ __launch_bounds__(256) void rowsq_kernel(const float* __restrict__ emb,
                                                    const float* __restrict__ x,
                                                    float* __restrict__ c2,
                                                    float* __restrict__ x2) {
  int b = blockIdx.x;
  int t = threadIdx.x;
  const float* src = (b < NCODES) ? (emb + (size_t)(VOFF + b) * D_DIM)
                                  : (x + (size_t)(b - NCODES) * D_DIM);
  float4 v = ((const float4*)src)[t];
  float s = v.x * v.x + v.y * v.y + v.z * v.z + v.w * v.w;
  for (int off = 32; off > 0; off >>= 1) s += __shfl_down(s, off, 64);
  __shared__ float red[4];
  if ((t & 63) == 0) red[t >> 6] = s;
  __syncthreads();
  if (t == 0) {
    float tot = red[0] + red[1] + red[2] + red[3];
    if (b < NCODES) c2[b] = tot; else x2[b - NCODES] = tot;
  }
}

// ---------------- bf16 MFMA distance GEMM ----------------
// MODE 0: per-(row,seg) approx min via atomicMin (fp32 bits)
// MODE 1: stash EXACT top-2 per (row,seg,128-q-tile), LDS-merged across the
//         two wc-waves (fixes the round-2 race where both waves clobbered
//         the same stash slot with their half-tile top-2)
// MODE 2: append candidates with dist <= minf + MARGIN_F
template<int MODE>
__global__ __launch_bounds__(256) void score_mfma_kernel(
    const float* __restrict__ x, const float* __restrict__ emb,
    const float* __restrict__ c2, const float* __restrict__ x2,
    unsigned* __restrict__ minf, unsigned* __restrict__ stash,
    unsigned* __restrict__ list, unsigned* __restrict__ cnt) {
  __shared__ short lA[2][BM][LDK];
  __shared__ short lB[2][BN][LDK];
  int tid = threadIdx.x;
  int m0 = blockIdx.x * BM, q0 = blockIdx.y * BN, seg = blockIdx.z;
  int lane = tid & 63, wid = tid >> 6;
  int wr = wid >> 1, wc = wid & 1;
  int lrow = lane & 15, kg = lane >> 4;

  int sr = tid >> 1;                 // 0..127: staged row
  int kh = (tid & 1) << 4;           // 0 or 16: k-half
  const float* abase = x + (size_t)(m0 + sr) * D_DIM + kh;
  int qg = q0 + sr; if (qg > QN - 1) qg = QN - 1;
  const float* bbase = emb + (size_t)(VOFF + seg * QN + qg) * D_DIM + kh;

  f32x4 acc[4][4];
#pragma unroll
  for (int i = 0; i < 4; i++)
#pragma unroll
    for (int j = 0; j < 4; j++) acc[i][j] = (f32x4){0.f, 0.f, 0.f, 0.f};

  float4 ra0, ra1, ra2, ra3, rb0, rb1, rb2, rb3;

#define LOAD_TILE(kt) {                                          \
    const float4* ap = (const float4*)(abase + (kt));            \
    const float4* bp = (const float4*)(bbase + (kt));            \
    ra0 = ap[0]; ra1 = ap[1]; ra2 = ap[2]; ra3 = ap[3];          \
    rb0 = bp[0]; rb1 = bp[1]; rb2 = bp[2]; rb3 = bp[3]; }

#define WRITE_TILE(bb) {                                                       \
    bf16x8 p0, p1, q0v, q1v;                                                   \
    p0[0]=f2bs(ra0.x); p0[1]=f2bs(ra0.y); p0[2]=f2bs(ra0.z); p0[3]=f2bs(ra0.w);\
    p0[4]=f2bs(ra1.x); p0[5]=f2bs(ra1.y); p0[6]=f2bs(ra1.z); p0[7]=f2bs(ra1.w);\
    p1[0]=f2bs(ra2.x); p1[1]=f2bs(ra2.y); p1[2]=f2bs(ra2.z); p1[3]=f2bs(ra2.w);\
    p1[4]=f2bs(ra3.x); p1[5]=f2bs(ra3.y); p1[6]=f2bs(ra3.z); p1[7]=f2bs(ra3.w);\
    q0v[0]=f2bs(rb0.x); q0v[1]=f2bs(rb0.y); q0v[2]=f2bs(rb0.z); q0v[3]=f2bs(rb0.w);\
    q0v[4]=f2bs(rb1.x); q0v[5]=f2bs(rb1.y); q0v[6]=f2bs(rb1.z); q0v[7]=f2bs(rb1.w);\
    q1v[0]=f2bs(rb2.x); q1v[1]=f2bs(rb2.y); q1v[2]=f2bs(rb2.z); q1v[3]=f2bs(rb2.w);\
    q1v[4]=f2bs(rb3.x); q1v[5]=f2bs(rb3.y); q1v[6]=f2bs(rb3.z); q1v[7]=f2bs(rb3.w);\
    *(bf16x8*)&lA[bb][sr][kh]     = p0;  *(bf16x8*)&lA[bb][sr][kh + 8] = p1;   \
    *(bf16x8*)&lB[bb][sr][kh]     = q0v; *(bf16x8*)&lB[bb][sr][kh + 8] = q1v; }

#define COMPUTE(bb) {                                                              \
    bf16x8 af0 = *(const bf16x8*)&lA[bb][wr * 64 +  0 + lrow][kg * 8];             \
    bf16x8 af1 = *(const bf16x8*)&lA[bb][wr * 64 + 16 + lrow][kg * 8];             \
    bf16x8 af2 = *(const bf16x8*)&lA[bb][wr * 64 + 32 + lrow][kg * 8];             \
    bf16x8 af3 = *(const bf16x8*)&lA[bb][wr * 64 + 48 + lrow][kg * 8];             \
    bf16x8 bg0 = *(const bf16x8*)&lB[bb][wc * 64 +  0 + lrow][kg * 8];             \
    bf16x8 bg1 = *(const bf16x8*)&lB[bb][wc * 64 + 16 + lrow][kg * 8];             \
    bf16x8 bg2 = *(const bf16x8*)&lB[bb][wc * 64 + 32 + lrow][kg * 8];             \
    bf16x8 bg3 = *(const bf16x8*)&lB[bb][wc * 64 + 48 + lrow][kg * 8];             \
    acc[0][0] = __builtin_amdgcn_mfma_f32_16x16x32_bf16(af0, bg0, acc[0][0],0,0,0);\
    acc[0][1] = __builtin_amdgcn_mfma_f32_16x16x32_bf16(af0, bg1, acc[0][1],0,0,0);\
    acc[0][2] = __builtin_amdgcn_mfma_f32_16x16x32_bf16(af0, bg2, acc[0][2],0,0,0);\
    acc[0][3] = __builtin_amdgcn_mfma_f32_16x16x32_bf16(af0, bg3, acc[0][3],0,0,0);\
    acc[1][0] = __builtin_amdgcn_mfma_f32_16x16x32_bf16(af1, bg0, acc[1][0],0,0,0);\
    acc[1][1] = __builtin_amdgcn_mfma_f32_16x16x32_bf16(af1, bg1, acc[1][1],0,0,0);\
    acc[1][2] = __builtin_amdgcn_mfma_f32_16x16x32_bf16(af1, bg2, acc[1][2],0,0,0);\
    acc[1][3] = __builtin_amdgcn_mfma_f32_16x16x32_bf16(af1, bg3, acc[1][3],0,0,0);\
    acc[2][0] = __builtin_amdgcn_mfma_f32_16x16x32_bf16(af2, bg0, acc[2][0],0,0,0);\
    acc[2][1] = __builtin_amdgcn_mfma_f32_16x16x32_bf16(af2, bg1, acc[2][1],0,0,0);\
    acc[2][2] = __builtin_amdgcn_mfma_f32_16x16x32_bf16(af2, bg2, acc[2][2],0,0,0);\
    acc[2][3] = __builtin_amdgcn_mfma_f32_16x16x32_bf16(af2, bg3, acc[2][3],0,0,0);\
    acc[3][0] = __builtin_amdgcn_mfma_f32_16x16x32_bf16(af3, bg0, acc[3][0],0,0,0);\
    acc[3][1] = __builtin_amdgcn_mfma_f32_16x16x32_bf16(af3, bg1, acc[3][1],0,0,0);\
    acc[3][2] = __builtin_amdgcn_mfma_f32_16x16x32_bf16(af3, bg2, acc[3][2],0,0,0);\
    acc[3][3] = __builtin_amdgcn_mfma_f32_16x16x32_bf16(af3, bg3, acc[3][3],0,0,0); }

  LOAD_TILE(0);
  WRITE_TILE(0);
  __syncthreads();
  int buf = 0;
  for (int kt = BK; kt < D_DIM; kt += BK) {
    LOAD_TILE(kt);
    COMPUTE(buf);
    WRITE_TILE(buf ^ 1);
    __syncthreads();
    buf ^= 1;
  }
  COMPUTE(buf);
  // D_DIM/BK = 32 tiles: prologue fills buf0, loop runs 31 iters, so the
  // final COMPUTE above reads buf==1. lA[0] (20KB) is dead from here on and
  // every wave passed the iter-31 barrier before reaching this point ->
  // safe to overlay the MODE-1 merge buffer on it.
  unsigned* mbuf = (unsigned*)&lA[0][0][0];   // mbuf[row128][wc][2]

  // ---- epilogue ----
  float c2v[4];
  bool  val[4];
  int   qloc[4];
#pragma unroll
  for (int nt = 0; nt < 4; nt++) {
    int ql = wc * 64 + nt * 16 + lrow;
    int q = q0 + ql;
    val[nt] = (q < QN);
    qloc[nt] = ql;
    c2v[nt] = c2[seg * QN + (val[nt] ? q : QN - 1)];
  }

#pragma unroll
  for (int mt = 0; mt < 4; mt++) {
#pragma unroll
    for (int r = 0; r < 4; r++) {
      int grow = m0 + wr * 64 + mt * 16 + kg * 4 + r;
      float x2r = x2[grow];
      if constexpr (MODE == 0) {
        float dmin = 1e30f;
#pragma unroll
        for (int nt = 0; nt < 4; nt++) {
          if (val[nt]) {
            float d = (x2r + c2v[nt]) - 2.0f * acc[mt][nt][r];
            dmin = fminf(dmin, d);
          }
        }
        dmin = fminf(dmin, __shfl_xor(dmin, 1, 64));
        dmin = fminf(dmin, __shfl_xor(dmin, 2, 64));
        dmin = fminf(dmin, __shfl_xor(dmin, 4, 64));
        dmin = fminf(dmin, __shfl_xor(dmin, 8, 64));
        if (lrow == 0)
          atomicMin(&minf[grow * NSEG + seg], __float_as_uint(fmaxf(dmin, 0.0f)));
      } else if constexpr (MODE == 1) {
        // wave-local top-2 over this wave's 64 q's (half-tile wc) — race-free
        unsigned b1 = 0xFFFFFFFFu, b2 = 0xFFFFFFFFu;
#pragma unroll
        for (int nt = 0; nt < 4; nt++) {
          unsigned u = 0xFFFFFFFFu;
          if (val[nt]) {
            float d = (x2r + c2v[nt]) - 2.0f * acc[mt][nt][r];
            float kq = (d - 1024.0f) * 16.0f;
            kq = fminf(fmaxf(kq, 0.0f), 65535.0f);
            u = (((unsigned)(int)kq) << 7) | (unsigned)qloc[nt];
          }
          if (u < b1) { b2 = b1; b1 = u; } else if (u < b2) b2 = u;
        }
#pragma unroll
        for (int m = 1; m < 16; m <<= 1) {
          unsigned o1 = shflx_u32(b1, m), o2 = shflx_u32(b2, m);
          unsigned n1 = min(b1, o1);
          unsigned n2 = min(max(b1, o1), min(b2, o2));
          b1 = n1; b2 = n2;
        }
        if (lrow == 0) {
          int rloc = wr * 64 + mt * 16 + kg * 4 + r;   // 0..127 row-in-block
          mbuf[(rloc * 2 + wc) * 2 + 0] = b1;
          mbuf[(rloc * 2 + wc) * 2 + 1] = b2;
        }
      } else {  // MODE 2
        float dm = __uint_as_float(minf[grow * NSEG + seg]) + MARGIN_F;
#pragma unroll
        for (int nt = 0; nt < 4; nt++) {
          if (val[nt]) {
            float d = (x2r + c2v[nt]) - 2.0f * acc[mt][nt][r];
            if (d <= dm) {
              unsigned idx = atomicAdd(cnt, 1u);
              if (idx < CAP)
                list[idx] = ((unsigned)grow << 15) | ((unsigned)seg << 12) |
                            (unsigned)(q0 + qloc[nt]);
            }
          }
        }
      }
    }
  }

  if constexpr (MODE == 1) {
    __syncthreads();
    // merge the two sorted half-tile pairs -> exact top-2 of the 128-q tile;
    // exactly one thread per row writes the stash slot (race fixed).
    if (tid < BM) {
      unsigned p1 = mbuf[(tid * 2 + 0) * 2 + 0];
      unsigned p2 = mbuf[(tid * 2 + 0) * 2 + 1];
      unsigned g1 = mbuf[(tid * 2 + 1) * 2 + 0];
      unsigned g2 = mbuf[(tid * 2 + 1) * 2 + 1];
      unsigned m1 = min(p1, g1);
      unsigned m2 = min(max(p1, g1), min(p2, g2));
      int grow = m0 + tid;
      size_t base = ((size_t)(grow * NSEG + seg) * 32 + blockIdx.y) * 2;
      stash[base + 0] = m1;
      stash[base + 1] = m2;
    }
  }
#undef LOAD_TILE
#undef WRITE_TILE
#undef COMPUTE
}

// ---------------- filter (path A): per-cell min over stash + margin qualify ----------------
__global__ __launch_bounds__(256) void filter_kernel(const unsigned* __restrict__ stash,
                                                     unsigned* __restrict__ list,
                                                     unsigned* __restrict__ cnt) {
  int waveid = blockIdx.x * 4 + (threadIdx.x >> 6);
  int lane = threadIdx.x & 63;
  unsigned e = stash[(size_t)waveid * 64 + lane];
  unsigned m = e;
  for (int msk = 1; msk < 64; msk <<= 1) m = min(m, shflx_u32(m, msk));
  unsigned kmin = m >> 7;
  if (e != 0xFFFFFFFFu && (e >> 7) <= kmin + MARGIN_Q) {
    int row = waveid >> 3, seg = waveid & 7;
    int q = (lane >> 1) * 128 + (int)(e & 127u);
    if (q < QN) {
      unsigned idx = atomicAdd(cnt, 1u);
      if (idx < CAP)
        list[idx] = ((unsigned)row << 15) | ((unsigned)seg << 12) | (unsigned)q;
    }
  }
}

// ---------------- exact fp32 rescore of candidates ----------------
__global__ __launch_bounds__(256) void rescore_kernel(const float* __restrict__ x,
                                                      const float* __restrict__ emb,
                                                      const float* __restrict__ c2,
                                                      const float* __restrict__ x2,
                                                      const unsigned* __restrict__ list,
                                                      const unsigned* __restrict__ cnt,
                                                      unsigned long long* __restrict__ cells) {
  int nw = gridDim.x * 4;
  int wv = blockIdx.x * 4 + (threadIdx.x >> 6);
  int lane = threadIdx.x & 63;
  unsigned n = *cnt; if (n > CAP) n = CAP;
  for (unsigned i = wv; i < n; i += nw) {
    unsigned e = list[i];
    int row = e >> 15, seg = (e >> 12) & 7, q = e & 4095;
    const float4* xr = (const float4*)(x + (size_t)row * D_DIM);
    const float4* cr = (const float4*)(emb + (size_t)(VOFF + seg * QN + q) * D_DIM);
    float s = 0.f;
#pragma unroll
    for (int j = 0; j < 4; j++) {
      float4 a = xr[j * 64 + lane];
      float4 b = cr[j * 64 + lane];
      s += a.x * b.x + a.y * b.y + a.z * b.z + a.w * b.w;
    }
    for (int msk = 1; msk < 64; msk <<= 1) s += __shfl_xor(s, msk, 64);
    float dist = (x2[row] + c2[seg * QN + q]) - 2.0f * s;
    unsigned u = __float_as_uint(dist);
    unsigned asc = (u & 0x80000000u) ? ~u : (u | 0x80000000u);
    unsigned key = ~asc;
    unsigned long long p = ((unsigned long long)key << 32) |
                           (unsigned long long)(~(unsigned)q);
    if (lane == 0) atomicMax(&cells[(size_t)row * NSEG + seg], p);
  }
}

// ---------------- gather + mse partial ----------------
__global__ __launch_bounds__(256) void gather_kernel(const float* __restrict__ x,
                                                     const float* __restrict__ emb,
                                                     const float* __restrict__ mask,
                                                     const unsigned long long* __restrict__ cells,
                                                     float* __restrict__ out,
                                                     double* __restrict__ part) {
  int n = blockIdx.x;
  int t = threadIdx.x;
  __shared__ int qsel[NSEG];
  if (t < NSEG) qsel[t] = (int)(~(unsigned)(cells[(size_t)n * NSEG + t] & 0xffffffffULL));
  __syncthreads();
  float4 xv = ((const float4*)(x + (size_t)n * D_DIM))[t];
  float ax = 0.f, ay = 0.f, az = 0.f, aw = 0.f;
#pragma unroll
  for (int s = 0; s < NSEG; s++) {
    float4 cv = ((const float4*)(emb + (size_t)(VOFF + s * QN + qsel[s]) * D_DIM))[t];
    ax += cv.x; ay += cv.y; az += cv.z; aw += cv.w;
  }
  float qx = ax * 0.125f, qy = ay * 0.125f, qz = az * 0.125f, qw = aw * 0.125f;
  float4 o4;
  o4.x = xv.x + (qx - xv.x);
  o4.y = xv.y + (qy - xv.y);
  o4.z = xv.z + (qz - xv.z);
  o4.w = xv.w + (qw - xv.w);
  ((float4*)(out + (size_t)n * D_DIM))[t] = o4;
  float mk = mask[n];
  float dx = qx * mk - xv.x * mk;
  float dy = qy * mk - xv.y * mk;
  float dz = qz * mk - xv.z * mk;
  float dw = qw * mk - xv.w * mk;
  float ss = dx * dx + dy * dy + dz * dz + dw * dw;
  double sd = (double)ss;
  for (int off = 32; off > 0; off >>= 1) sd += __shfl_down(sd, off, 64);
  __shared__ double red[4];
  if ((t & 63) == 0) red[t >> 6] = sd;
  __syncthreads();
  if (t == 0) part[n] = red[0] + red[1] + red[2] + red[3];
}

__global__ __launch_bounds__(256) void finalize_kernel(const double* __restrict__ part,
                                                       float* __restrict__ loss_out) {
  int t = threadIdx.x;
  double s = 0.0;
  for (int i = t; i < NROWS; i += 256) s += part[i];
  for (int off = 32; off > 0; off >>= 1) s += __shfl_down(s, off, 64);
  __shared__ double red[4];
  if ((t & 63) == 0) red[t >> 6] = s;
  __syncthreads();
  if (t == 0) {
    double tot = red[0] + red[1] + red[2] + red[3];
    float m = (float)(tot / (double)((size_t)NROWS * D_DIM));
    loss_out[0] = m + 0.25f * m;
  }
}

extern "C" void kernel_launch(void* const* d_in, const int* in_sizes, int n_in,
                              void* d_out, int out_size, void* d_ws, size_t ws_size,
                              hipStream_t stream) {
  const float* x    = (const float*)d_in[0];
  const float* emb  = (const float*)d_in[1];
  const float* mask = (const float*)d_in[2];
  (void)in_sizes; (void)n_in; (void)out_size;

  char* ws = (char*)d_ws;
  float* c2 = (float*)(ws + C2_OFF);
  float* x2 = (float*)(ws + X2_OFF);
  unsigned long long* cells = (unsigned long long*)(ws + CELLS_OFF);
  unsigned* minf = (unsigned*)(ws + MINF_OFF);
  unsigned* cnt  = (unsigned*)(ws + CNT_OFF);
  double*   part = (double*)(ws + PART_OFF);
  unsigned* list = (unsigned*)(ws + LIST_OFF);
  unsigned* stash = (unsigned*)(ws + STASH_OFF);
  float* out = (float*)d_out;

  bool bigws = (ws_size >= (size_t)WS_NEED_A);

  hipMemsetAsync(cells, 0, 262144, stream);
  hipMemsetAsync(minf, 0xFF, 131072, stream);
  hipMemsetAsync(cnt, 0, 256, stream);

  rowsq_kernel<<<dim3(NCODES + NROWS), 256, 0, stream>>>(emb, x, c2, x2);

  if (bigws) {
    score_mfma_kernel<1><<<dim3(NROWS / BM, (QN + BN - 1) / BN, NSEG), 256, 0, stream>>>(
        x, emb, c2, x2, minf, stash, list, cnt);
    filter_kernel<<<dim3(8192), 256, 0, stream>>>(stash, list, cnt);
  } else {
    score_mfma_kernel<0><<<dim3(NROWS / BM, (QN + BN - 1) / BN, NSEG), 256, 0, stream>>>(
        x, emb, c2, x2, minf, stash, list, cnt);
    score_mfma_kernel<2><<<dim3(NROWS / BM, (QN + BN - 1) / BN, NSEG), 256, 0, stream>>>(
        x, emb, c2, x2, minf, stash, list, cnt);
  }
  rescore_kernel<<<dim3(1024), 256, 0, stream>>>(x, emb, c2, x2, list, cnt, cells);
  gather_kernel<<<dim3(NROWS), 256, 0, stream>>>(x, emb, mask, cells, out, part);
  finalize_kernel<<<dim3(1), 256, 0, stream>>>(part, out + (size_t)NROWS * D_DIM);
}

// Round 4
// 859.122 us; speedup vs baseline: 3.6984x; 1.5624x over previous
//
#include <hip/hip_runtime.h>
#include <stdint.h>

#define D_DIM  1024
#define NROWS  4096
#define NSEG   8
#define QN     4000
#define NCODES 32000
#define VOFF   2

#define BM 128
#define BN 128
#define BK 32
#define LDK 40           // padded k-stride in shorts (80B rows) — round-3 fallback kernel

#define MARGIN_F 4.0f
#define MARGIN_Q 66      // 4.0*16 + quantization slack
#define CAP      262144u

// ws layout (bytes)
#define C2_OFF     0u
#define X2_OFF     131072u
#define CELLS_OFF  147456u
#define MINF_OFF   409600u
#define CNT_OFF    540672u
#define PART_OFF   540928u
#define LIST_OFF   573696u
#define STASH_OFF  1622272u
#define WS_NEED_A  10010880u
// fast path: bf16 copies of x and codes
#define XBF_OFF    10010880u
#define CBF_OFF    18399488u
#define WS_NEED_FAST 83935488u

typedef short bf16x8 __attribute__((ext_vector_type(8)));
typedef float f32x4  __attribute__((ext_vector_type(4)));

#define AS1(p) ((const __attribute__((address_space(1))) void*)(p))
#define AS3(p) ((__attribute__((address_space(3))) void*)(p))

__device__ inline unsigned short f2bs(float f) {   // fp32 -> bf16 RNE, finite inputs
  unsigned u = __float_as_uint(f);
  unsigned r = (u + 0x7FFFu + ((u >> 16) & 1u)) >> 16;
  return (unsigned short)r;
}
__device__ inline unsigned shflx_u32(unsigned v, int m) {
  return (unsigned)__shfl_xor((int)v, m, 64);
}

// ---------------- rowsq: c2 / x2 (fallback path) ----------------
__global__ __launch_bounds__(256) void rowsq_kernel(const float* __restrict__ emb,
                                                    const float* __restrict__ x,
                                                    float* __restrict__ c2,
                                                    float* __restrict__ x2) {
  int b = blockIdx.x;
  int t = threadIdx.x;
  const float* src = (b < NCODES) ? (emb + (size_t)(VOFF + b) * D_DIM)
                                  : (x + (size_t)(b - NCODES) * D_DIM);
  float4 v = ((const float4*)src)[t];
  float s = v.x * v.x + v.y * v.y + v.z * v.z + v.w * v.w;
  for (int off = 32; off > 0; off >>= 1) s += __shfl_down(s, off, 64);
  __shared__ float red[4];
  if ((t & 63) == 0) red[t >> 6] = s;
  __syncthreads();
  if (t == 0) {
    float tot = red[0] + red[1] + red[2] + red[3];
    if (b < NCODES) c2[b] = tot; else x2[b - NCODES] = tot;
  }
}

// ---------------- convert: fp32 -> bf16 copies + c2/x2 (fast path) ----------------
__global__ __launch_bounds__(256) void convert_kernel(const float* __restrict__ emb,
                                                      const float* __restrict__ x,
                                                      unsigned short* __restrict__ cbf,
                                                      unsigned short* __restrict__ xbf,
                                                      float* __restrict__ c2,
                                                      float* __restrict__ x2) {
  int b = blockIdx.x;
  int t = threadIdx.x;
  const float* src;
  unsigned short* dst;
  if (b < NCODES) { src = emb + (size_t)(VOFF + b) * D_DIM; dst = cbf + (size_t)b * D_DIM; }
  else            { src = x + (size_t)(b - NCODES) * D_DIM; dst = xbf + (size_t)(b - NCODES) * D_DIM; }
  float4 v = ((const float4*)src)[t];
  ushort4 o;
  o.x = f2bs(v.x); o.y = f2bs(v.y); o.z = f2bs(v.z); o.w = f2bs(v.w);
  ((ushort4*)dst)[t] = o;
  float s = v.x * v.x + v.y * v.y + v.z * v.z + v.w * v.w;
  for (int off = 32; off > 0; off >>= 1) s += __shfl_down(s, off, 64);
  __shared__ float red[4];
  if ((t & 63) == 0) red[t >> 6] = s;
  __syncthreads();
  if (t == 0) {
    float tot = red[0] + red[1] + red[2] + red[3];
    if (b < NCODES) c2[b] = tot; else x2[b - NCODES] = tot;
  }
}

// ---------------- FAST bf16 MFMA distance GEMM (m97 structure) ----------------
// global_load_lds width-16 direct staging from pre-converted bf16 buffers,
// linear LDS [128][32], 2-phase double buffer. Epilogue = exact top-2 per
// (row,seg,128-q-tile) with cross-wave LDS merge (same as fallback MODE 1).
__global__ __launch_bounds__(256) void score_fast_kernel(
    const unsigned short* __restrict__ xbf, const unsigned short* __restrict__ cbf,
    const float* __restrict__ c2, const float* __restrict__ x2,
    unsigned* __restrict__ stash) {
  __shared__ short lA[2][BM][BK];
  __shared__ short lB[2][BN][BK];
  int tid = threadIdx.x;
  int m0 = blockIdx.x * BM, q0 = blockIdx.y * BN, seg = blockIdx.z;
  int lane = tid & 63, wid = tid >> 6;
  int wr = wid >> 1, wc = wid & 1;
  int lrow = lane & 15, kg = lane >> 4;

  // staging: thread t covers row t>>2 (and +64), 8 shorts at col (t&3)*8
  int srow = tid >> 2;
  int scol = (tid & 3) << 3;
  const unsigned short* aSrc0 = xbf + (size_t)(m0 + srow) * D_DIM + scol;
  const unsigned short* aSrc1 = aSrc0 + (size_t)64 * D_DIM;
  int qb0 = q0 + srow;      if (qb0 > QN - 1) qb0 = QN - 1;
  int qb1 = q0 + srow + 64; if (qb1 > QN - 1) qb1 = QN - 1;
  const unsigned short* bSrc0 = cbf + (size_t)(seg * QN + qb0) * D_DIM + scol;
  const unsigned short* bSrc1 = cbf + (size_t)(seg * QN + qb1) * D_DIM + scol;
  int ldsOff = tid << 3;   // shorts: linear byte offset tid*16 within half-tile

  f32x4 acc[4][4];
#pragma unroll
  for (int i = 0; i < 4; i++)
#pragma unroll
    for (int j = 0; j < 4; j++) acc[i][j] = (f32x4){0.f, 0.f, 0.f, 0.f};

#define STAGE_F(bb, kt) {                                                            \
    __builtin_amdgcn_global_load_lds(AS1(aSrc0 + (kt)), AS3(&lA[bb][0][0]  + ldsOff), 16, 0, 0); \
    __builtin_amdgcn_global_load_lds(AS1(aSrc1 + (kt)), AS3(&lA[bb][64][0] + ldsOff), 16, 0, 0); \
    __builtin_amdgcn_global_load_lds(AS1(bSrc0 + (kt)), AS3(&lB[bb][0][0]  + ldsOff), 16, 0, 0); \
    __builtin_amdgcn_global_load_lds(AS1(bSrc1 + (kt)), AS3(&lB[bb][64][0] + ldsOff), 16, 0, 0); }

#define COMPUTE_F(bb) {                                                            \
    bf16x8 af0 = *(const bf16x8*)&lA[bb][wr * 64 +  0 + lrow][kg * 8];             \
    bf16x8 af1 = *(const bf16x8*)&lA[bb][wr * 64 + 16 + lrow][kg * 8];             \
    bf16x8 af2 = *(const bf16x8*)&lA[bb][wr * 64 + 32 + lrow][kg * 8];             \
    bf16x8 af3 = *(const bf16x8*)&lA[bb][wr * 64 + 48 + lrow][kg * 8];             \
    bf16x8 bg0 = *(const bf16x8*)&lB[bb][wc * 64 +  0 + lrow][kg * 8];             \
    bf16x8 bg1 = *(const bf16x8*)&lB[bb][wc * 64 + 16 + lrow][kg * 8];             \
    bf16x8 bg2 = *(const bf16x8*)&lB[bb][wc * 64 + 32 + lrow][kg * 8];             \
    bf16x8 bg3 = *(const bf16x8*)&lB[bb][wc * 64 + 48 + lrow][kg * 8];             \
    acc[0][0] = __builtin_amdgcn_mfma_f32_16x16x32_bf16(af0, bg0, acc[0][0],0,0,0);\
    acc[0][1] = __builtin_amdgcn_mfma_f32_16x16x32_bf16(af0, bg1, acc[0][1],0,0,0);\
    acc[0][2] = __builtin_amdgcn_mfma_f32_16x16x32_bf16(af0, bg2, acc[0][2],0,0,0);\
    acc[0][3] = __builtin_amdgcn_mfma_f32_16x16x32_bf16(af0, bg3, acc[0][3],0,0,0);\
    acc[1][0] = __builtin_amdgcn_mfma_f32_16x16x32_bf16(af1, bg0, acc[1][0],0,0,0);\
    acc[1][1] = __builtin_amdgcn_mfma_f32_16x16x32_bf16(af1, bg1, acc[1][1],0,0,0);\
    acc[1][2] = __builtin_amdgcn_mfma_f32_16x16x32_bf16(af1, bg2, acc[1][2],0,0,0);\
    acc[1][3] = __builtin_amdgcn_mfma_f32_16x16x32_bf16(af1, bg3, acc[1][3],0,0,0);\
    acc[2][0] = __builtin_amdgcn_mfma_f32_16x16x32_bf16(af2, bg0, acc[2][0],0,0,0);\
    acc[2][1] = __builtin_amdgcn_mfma_f32_16x16x32_bf16(af2, bg1, acc[2][1],0,0,0);\
    acc[2][2] = __builtin_amdgcn_mfma_f32_16x16x32_bf16(af2, bg2, acc[2][2],0,0,0);\
    acc[2][3] = __builtin_amdgcn_mfma_f32_16x16x32_bf16(af2, bg3, acc[2][3],0,0,0);\
    acc[3][0] = __builtin_amdgcn_mfma_f32_16x16x32_bf16(af3, bg0, acc[3][0],0,0,0);\
    acc[3][1] = __builtin_amdgcn_mfma_f32_16x16x32_bf16(af3, bg1, acc[3][1],0,0,0);\
    acc[3][2] = __builtin_amdgcn_mfma_f32_16x16x32_bf16(af3, bg2, acc[3][2],0,0,0);\
    acc[3][3] = __builtin_amdgcn_mfma_f32_16x16x32_bf16(af3, bg3, acc[3][3],0,0,0); }

  STAGE_F(0, 0);
  __syncthreads();
  int buf = 0;
  for (int kt = BK; kt < D_DIM; kt += BK) {   // 31 iterations
    STAGE_F(buf ^ 1, kt);
    COMPUTE_F(buf);
    __syncthreads();
    buf ^= 1;
  }
  COMPUTE_F(buf);   // buf==1; lA[0] dead (last read iter 30, barrier passed)
  unsigned* mbuf = (unsigned*)&lA[0][0][0];   // mbuf[row128][wc][2], 2KB

  float c2v[4];
  bool  val[4];
  int   qloc[4];
#pragma unroll
  for (int nt = 0; nt < 4; nt++) {
    int ql = wc * 64 + nt * 16 + lrow;
    int q = q0 + ql;
    val[nt] = (q < QN);
    qloc[nt] = ql;
    c2v[nt] = c2[seg * QN + (val[nt] ? q : QN - 1)];
  }

#pragma unroll
  for (int mt = 0; mt < 4; mt++) {
#pragma unroll
    for (int r = 0; r < 4; r++) {
      int grow = m0 + wr * 64 + mt * 16 + kg * 4 + r;
      float x2r = x2[grow];
      unsigned b1 = 0xFFFFFFFFu, b2 = 0xFFFFFFFFu;
#pragma unroll
      for (int nt = 0; nt < 4; nt++) {
        unsigned u = 0xFFFFFFFFu;
        if (val[nt]) {
          float d = (x2r + c2v[nt]) - 2.0f * acc[mt][nt][r];
          float kq = (d - 1024.0f) * 16.0f;
          kq = fminf(fmaxf(kq, 0.0f), 65535.0f);
          u = (((unsigned)(int)kq) << 7) | (unsigned)qloc[nt];
        }
        if (u < b1) { b2 = b1; b1 = u; } else if (u < b2) b2 = u;
      }
#pragma unroll
      for (int m = 1; m < 16; m <<= 1) {
        unsigned o1 = shflx_u32(b1, m), o2 = shflx_u32(b2, m);
        unsigned n1 = min(b1, o1);
        unsigned n2 = min(max(b1, o1), min(b2, o2));
        b1 = n1; b2 = n2;
      }
      if (lrow == 0) {
        int rloc = wr * 64 + mt * 16 + kg * 4 + r;
        mbuf[(rloc * 2 + wc) * 2 + 0] = b1;
        mbuf[(rloc * 2 + wc) * 2 + 1] = b2;
      }
    }
  }
  __syncthreads();
  if (tid < BM) {
    unsigned p1 = mbuf[(tid * 2 + 0) * 2 + 0];
    unsigned p2 = mbuf[(tid * 2 + 0) * 2 + 1];
    unsigned g1 = mbuf[(tid * 2 + 1) * 2 + 0];
    unsigned g2 = mbuf[(tid * 2 + 1) * 2 + 1];
    unsigned m1 = min(p1, g1);
    unsigned m2 = min(max(p1, g1), min(p2, g2));
    int grow = m0 + tid;
    size_t base = ((size_t)(grow * NSEG + seg) * 32 + blockIdx.y) * 2;
    stash[base + 0] = m1;
    stash[base + 1] = m2;
  }
#undef STAGE_F
#undef COMPUTE_F
}

// ---------------- fallback bf16 MFMA GEMM (round-3, known-good) ----------------
template<int MODE>
__global__ __launch_bounds__(256) void score_mfma_kernel(
    const float* __restrict__ x, const float* __restrict__ emb,
    const float* __restrict__ c2, const float* __restrict__ x2,
    unsigned* __restrict__ minf, unsigned* __restrict__ stash,
    unsigned* __restrict__ list, unsigned* __restrict__ cnt) {
  __shared__ short lA[2][BM][LDK];
  __shared__ short lB[2][BN][LDK];
  int tid = threadIdx.x;
  int m0 = blockIdx.x * BM, q0 = blockIdx.y * BN, seg = blockIdx.z;
  int lane = tid & 63, wid = tid >> 6;
  int wr = wid >> 1, wc = wid & 1;
  int lrow = lane & 15, kg = lane >> 4;

  int sr = tid >> 1;
  int kh = (tid & 1) << 4;
  const float* abase = x + (size_t)(m0 + sr) * D_DIM + kh;
  int qg = q0 + sr; if (qg > QN - 1) qg = QN - 1;
  const float* bbase = emb + (size_t)(VOFF + seg * QN + qg) * D_DIM + kh;

  f32x4 acc[4][4];
#pragma unroll
  for (int i = 0; i < 4; i++)
#pragma unroll
    for (int j = 0; j < 4; j++) acc[i][j] = (f32x4){0.f, 0.f, 0.f, 0.f};

  float4 ra0, ra1, ra2, ra3, rb0, rb1, rb2, rb3;

#define LOAD_TILE(kt) {                                          \
    const float4* ap = (const float4*)(abase + (kt));            \
    const float4* bp = (const float4*)(bbase + (kt));            \
    ra0 = ap[0]; ra1 = ap[1]; ra2 = ap[2]; ra3 = ap[3];          \
    rb0 = bp[0]; rb1 = bp[1]; rb2 = bp[2]; rb3 = bp[3]; }

#define WRITE_TILE(bb) {                                                       \
    bf16x8 p0, p1, q0v, q1v;                                                   \
    p0[0]=f2bs(ra0.x); p0[1]=f2bs(ra0.y); p0[2]=f2bs(ra0.z); p0[3]=f2bs(ra0.w);\
    p0[4]=f2bs(ra1.x); p0[5]=f2bs(ra1.y); p0[6]=f2bs(ra1.z); p0[7]=f2bs(ra1.w);\
    p1[0]=f2bs(ra2.x); p1[1]=f2bs(ra2.y); p1[2]=f2bs(ra2.z); p1[3]=f2bs(ra2.w);\
    p1[4]=f2bs(ra3.x); p1[5]=f2bs(ra3.y); p1[6]=f2bs(ra3.z); p1[7]=f2bs(ra3.w);\
    q0v[0]=f2bs(rb0.x); q0v[1]=f2bs(rb0.y); q0v[2]=f2bs(rb0.z); q0v[3]=f2bs(rb0.w);\
    q0v[4]=f2bs(rb1.x); q0v[5]=f2bs(rb1.y); q0v[6]=f2bs(rb1.z); q0v[7]=f2bs(rb1.w);\
    q1v[0]=f2bs(rb2.x); q1v[1]=f2bs(rb2.y); q1v[2]=f2bs(rb2.z); q1v[3]=f2bs(rb2.w);\
    q1v[4]=f2bs(rb3.x); q1v[5]=f2bs(rb3.y); q1v[6]=f2bs(rb3.z); q1v[7]=f2bs(rb3.w);\
    *(bf16x8*)&lA[bb][sr][kh]     = p0;  *(bf16x8*)&lA[bb][sr][kh + 8] = p1;   \
    *(bf16x8*)&lB[bb][sr][kh]     = q0v; *(bf16x8*)&lB[bb][sr][kh + 8] = q1v; }

#define COMPUTE(bb) {                                                              \
    bf16x8 af0 = *(const bf16x8*)&lA[bb][wr * 64 +  0 + lrow][kg * 8];             \
    bf16x8 af1 = *(const bf16x8*)&lA[bb][wr * 64 + 16 + lrow][kg * 8];             \
    bf16x8 af2 = *(const bf16x8*)&lA[bb][wr * 64 + 32 + lrow][kg * 8];             \
    bf16x8 af3 = *(const bf16x8*)&lA[bb][wr * 64 + 48 + lrow][kg * 8];             \
    bf16x8 bg0 = *(const bf16x8*)&lB[bb][wc * 64 +  0 + lrow][kg * 8];             \
    bf16x8 bg1 = *(const bf16x8*)&lB[bb][wc * 64 + 16 + lrow][kg * 8];             \
    bf16x8 bg2 = *(const bf16x8*)&lB[bb][wc * 64 + 32 + lrow][kg * 8];             \
    bf16x8 bg3 = *(const bf16x8*)&lB[bb][wc * 64 + 48 + lrow][kg * 8];             \
    acc[0][0] = __builtin_amdgcn_mfma_f32_16x16x32_bf16(af0, bg0, acc[0][0],0,0,0);\
    acc[0][1] = __builtin_amdgcn_mfma_f32_16x16x32_bf16(af0, bg1, acc[0][1],0,0,0);\
    acc[0][2] = __builtin_amdgcn_mfma_f32_16x16x32_bf16(af0, bg2, acc[0][2],0,0,0);\
    acc[0][3] = __builtin_amdgcn_mfma_f32_16x16x32_bf16(af0, bg3, acc[0][3],0,0,0);\
    acc[1][0] = __builtin_amdgcn_mfma_f32_16x16x32_bf16(af1, bg0, acc[1][0],0,0,0);\
    acc[1][1] = __builtin_amdgcn_mfma_f32_16x16x32_bf16(af1, bg1, acc[1][1],0,0,0);\
    acc[1][2] = __builtin_amdgcn_mfma_f32_16x16x32_bf16(af1, bg2, acc[1][2],0,0,0);\
    acc[1][3] = __builtin_amdgcn_mfma_f32_16x16x32_bf16(af1, bg3, acc[1][3],0,0,0);\
    acc[2][0] = __builtin_amdgcn_mfma_f32_16x16x32_bf16(af2, bg0, acc[2][0],0,0,0);\
    acc[2][1] = __builtin_amdgcn_mfma_f32_16x16x32_bf16(af2, bg1, acc[2][1],0,0,0);\
    acc[2][2] = __builtin_amdgcn_mfma_f32_16x16x32_bf16(af2, bg2, acc[2][2],0,0,0);\
    acc[2][3] = __builtin_amdgcn_mfma_f32_16x16x32_bf16(af2, bg3, acc[2][3],0,0,0);\
    acc[3][0] = __builtin_amdgcn_mfma_f32_16x16x32_bf16(af3, bg0, acc[3][0],0,0,0);\
    acc[3][1] = __builtin_amdgcn_mfma_f32_16x16x32_bf16(af3, bg1, acc[3][1],0,0,0);\
    acc[3][2] = __builtin_amdgcn_mfma_f32_16x16x32_bf16(af3, bg2, acc[3][2],0,0,0);\
    acc[3][3] = __builtin_amdgcn_mfma_f32_16x16x32_bf16(af3, bg3, acc[3][3],0,0,0); }

  LOAD_TILE(0);
  WRITE_TILE(0);
  __syncthreads();
  int buf = 0;
  for (int kt = BK; kt < D_DIM; kt += BK) {
    LOAD_TILE(kt);
    COMPUTE(buf);
    WRITE_TILE(buf ^ 1);
    __syncthreads();
    buf ^= 1;
  }
  COMPUTE(buf);
  unsigned* mbuf = (unsigned*)&lA[0][0][0];

  float c2v[4];
  bool  val[4];
  int   qloc[4];
#pragma unroll
  for (int nt = 0; nt < 4; nt++) {
    int ql = wc * 64 + nt * 16 + lrow;
    int q = q0 + ql;
    val[nt] = (q < QN);
    qloc[nt] = ql;
    c2v[nt] = c2[seg * QN + (val[nt] ? q : QN - 1)];
  }

#pragma unroll
  for (int mt = 0; mt < 4; mt++) {
#pragma unroll
    for (int r = 0; r < 4; r++) {
      int grow = m0 + wr * 64 + mt * 16 + kg * 4 + r;
      float x2r = x2[grow];
      if constexpr (MODE == 0) {
        float dmin = 1e30f;
#pragma unroll
        for (int nt = 0; nt < 4; nt++) {
          if (val[nt]) {
            float d = (x2r + c2v[nt]) - 2.0f * acc[mt][nt][r];
            dmin = fminf(dmin, d);
          }
        }
        dmin = fminf(dmin, __shfl_xor(dmin, 1, 64));
        dmin = fminf(dmin, __shfl_xor(dmin, 2, 64));
        dmin = fminf(dmin, __shfl_xor(dmin, 4, 64));
        dmin = fminf(dmin, __shfl_xor(dmin, 8, 64));
        if (lrow == 0)
          atomicMin(&minf[grow * NSEG + seg], __float_as_uint(fmaxf(dmin, 0.0f)));
      } else if constexpr (MODE == 1) {
        unsigned b1 = 0xFFFFFFFFu, b2 = 0xFFFFFFFFu;
#pragma unroll
        for (int nt = 0; nt < 4; nt++) {
          unsigned u = 0xFFFFFFFFu;
          if (val[nt]) {
            float d = (x2r + c2v[nt]) - 2.0f * acc[mt][nt][r];
            float kq = (d - 1024.0f) * 16.0f;
            kq = fminf(fmaxf(kq, 0.0f), 65535.0f);
            u = (((unsigned)(int)kq) << 7) | (unsigned)qloc[nt];
          }
          if (u < b1) { b2 = b1; b1 = u; } else if (u < b2) b2 = u;
        }
#pragma unroll
        for (int m = 1; m < 16; m <<= 1) {
          unsigned o1 = shflx_u32(b1, m), o2 = shflx_u32(b2, m);
          unsigned n1 = min(b1, o1);
          unsigned n2 = min(max(b1, o1), min(b2, o2));
          b1 = n1; b2 = n2;
        }
        if (lrow == 0) {
          int rloc = wr * 64 + mt * 16 + kg * 4 + r;
          mbuf[(rloc * 2 + wc) * 2 + 0] = b1;
          mbuf[(rloc * 2 + wc) * 2 + 1] = b2;
        }
      } else {
        float dm = __uint_as_float(minf[grow * NSEG + seg]) + MARGIN_F;
#pragma unroll
        for (int nt = 0; nt < 4; nt++) {
          if (val[nt]) {
            float d = (x2r + c2v[nt]) - 2.0f * acc[mt][nt][r];
            if (d <= dm) {
              unsigned idx = atomicAdd(cnt, 1u);
              if (idx < CAP)
                list[idx] = ((unsigned)grow << 15) | ((unsigned)seg << 12) |
                            (unsigned)(q0 + qloc[nt]);
            }
          }
        }
      }
    }
  }

  if constexpr (MODE == 1) {
    __syncthreads();
    if (tid < BM) {
      unsigned p1 = mbuf[(tid * 2 + 0) * 2 + 0];
      unsigned p2 = mbuf[(tid * 2 + 0) * 2 + 1];
      unsigned g1 = mbuf[(tid * 2 + 1) * 2 + 0];
      unsigned g2 = mbuf[(tid * 2 + 1) * 2 + 1];
      unsigned m1 = min(p1, g1);
      unsigned m2 = min(max(p1, g1), min(p2, g2));
      int grow = m0 + tid;
      size_t base = ((size_t)(grow * NSEG + seg) * 32 + blockIdx.y) * 2;
      stash[base + 0] = m1;
      stash[base + 1] = m2;
    }
  }
#undef LOAD_TILE
#undef WRITE_TILE
#undef COMPUTE
}

// ---------------- filter: per-cell min over stash + margin qualify ----------------
__global__ __launch_bounds__(256) void filter_kernel(const unsigned* __restrict__ stash,
                                                     unsigned* __restrict__ list,
                                                     unsigned* __restrict__ cnt) {
  int waveid = blockIdx.x * 4 + (threadIdx.x >> 6);
  int lane = threadIdx.x & 63;
  unsigned e = stash[(size_t)waveid * 64 + lane];
  unsigned m = e;
  for (int msk = 1; msk < 64; msk <<= 1) m = min(m, shflx_u32(m, msk));
  unsigned kmin = m >> 7;
  if (e != 0xFFFFFFFFu && (e >> 7) <= kmin + MARGIN_Q) {
    int row = waveid >> 3, seg = waveid & 7;
    int q = (lane >> 1) * 128 + (int)(e & 127u);
    if (q < QN) {
      unsigned idx = atomicAdd(cnt, 1u);
      if (idx < CAP)
        list[idx] = ((unsigned)row << 15) | ((unsigned)seg << 12) | (unsigned)q;
    }
  }
}

// ---------------- exact fp32 rescore of candidates ----------------
__global__ __launch_bounds__(256) void rescore_kernel(const float* __restrict__ x,
                                                      const float* __restrict__ emb,
                                                      const float* __restrict__ c2,
                                                      const float* __restrict__ x2,
                                                      const unsigned* __restrict__ list,
                                                      const unsigned* __restrict__ cnt,
                                                      unsigned long long* __restrict__ cells) {
  int nw = gridDim.x * 4;
  int wv = blockIdx.x * 4 + (threadIdx.x >> 6);
  int lane = threadIdx.x & 63;
  unsigned n = *cnt; if (n > CAP) n = CAP;
  for (unsigned i = wv; i < n; i += nw) {
    unsigned e = list[i];
    int row = e >> 15, seg = (e >> 12) & 7, q = e & 4095;
    const float4* xr = (const float4*)(x + (size_t)row * D_DIM);
    const float4* cr = (const float4*)(emb + (size_t)(VOFF + seg * QN + q) * D_DIM);
    float s = 0.f;
#pragma unroll
    for (int j = 0; j < 4; j++) {
      float4 a = xr[j * 64 + lane];
      float4 b = cr[j * 64 + lane];
      s += a.x * b.x + a.y * b.y + a.z * b.z + a.w * b.w;
    }
    for (int msk = 1; msk < 64; msk <<= 1) s += __shfl_xor(s, msk, 64);
    float dist = (x2[row] + c2[seg * QN + q]) - 2.0f * s;
    unsigned u = __float_as_uint(dist);
    unsigned asc = (u & 0x80000000u) ? ~u : (u | 0x80000000u);
    unsigned key = ~asc;
    unsigned long long p = ((unsigned long long)key << 32) |
                           (unsigned long long)(~(unsigned)q);
    if (lane == 0) atomicMax(&cells[(size_t)row * NSEG + seg], p);
  }
}

// ---------------- gather + mse partial ----------------
__global__ __launch_bounds__(256) void gather_kernel(const float* __restrict__ x,
                                                     const float* __restrict__ emb,
                                                     const float* __restrict__ mask,
                                                     const unsigned long long* __restrict__ cells,
                                                     float* __restrict__ out,
                                                     double* __restrict__ part) {
  int n = blockIdx.x;
  int t = threadIdx.x;
  __shared__ int qsel[NSEG];
  if (t < NSEG) qsel[t] = (int)(~(unsigned)(cells[(size_t)n * NSEG + t] & 0xffffffffULL));
  __syncthreads();
  float4 xv = ((const float4*)(x + (size_t)n * D_DIM))[t];
  float ax = 0.f, ay = 0.f, az = 0.f, aw = 0.f;
#pragma unroll
  for (int s = 0; s < NSEG; s++) {
    float4 cv = ((const float4*)(emb + (size_t)(VOFF + s * QN + qsel[s]) * D_DIM))[t];
    ax += cv.x; ay += cv.y; az += cv.z; aw += cv.w;
  }
  float qx = ax * 0.125f, qy = ay * 0.125f, qz = az * 0.125f, qw = aw * 0.125f;
  float4 o4;
  o4.x = xv.x + (qx - xv.x);
  o4.y = xv.y + (qy - xv.y);
  o4.z = xv.z + (qz - xv.z);
  o4.w = xv.w + (qw - xv.w);
  ((float4*)(out + (size_t)n * D_DIM))[t] = o4;
  float mk = mask[n];
  float dx = qx * mk - xv.x * mk;
  float dy = qy * mk - xv.y * mk;
  float dz = qz * mk - xv.z * mk;
  float dw = qw * mk - xv.w * mk;
  float ss = dx * dx + dy * dy + dz * dz + dw * dw;
  double sd = (double)ss;
  for (int off = 32; off > 0; off >>= 1) sd += __shfl_down(sd, off, 64);
  __shared__ double red[4];
  if ((t & 63) == 0) red[t >> 6] = sd;
  __syncthreads();
  if (t == 0) part[n] = red[0] + red[1] + red[2] + red[3];
}

__global__ __launch_bounds__(256) void finalize_kernel(const double* __restrict__ part,
                                                       float* __restrict__ loss_out) {
  int t = threadIdx.x;
  double s = 0.0;
  for (int i = t; i < NROWS; i += 256) s += part[i];
  for (int off = 32; off > 0; off >>= 1) s += __shfl_down(s, off, 64);
  __shared__ double red[4];
  if ((t & 63) == 0) red[t >> 6] = s;
  __syncthreads();
  if (t == 0) {
    double tot = red[0] + red[1] + red[2] + red[3];
    float m = (float)(tot / (double)((size_t)NROWS * D_DIM));
    loss_out[0] = m + 0.25f * m;
  }
}

extern "C" void kernel_launch(void* const* d_in, const int* in_sizes, int n_in,
                              void* d_out, int out_size, void* d_ws, size_t ws_size,
                              hipStream_t stream) {
  const float* x    = (const float*)d_in[0];
  const float* emb  = (const float*)d_in[1];
  const float* mask = (const float*)d_in[2];
  (void)in_sizes; (void)n_in; (void)out_size;

  char* ws = (char*)d_ws;
  float* c2 = (float*)(ws + C2_OFF);
  float* x2 = (float*)(ws + X2_OFF);
  unsigned long long* cells = (unsigned long long*)(ws + CELLS_OFF);
  unsigned* minf = (unsigned*)(ws + MINF_OFF);
  unsigned* cnt  = (unsigned*)(ws + CNT_OFF);
  double*   part = (double*)(ws + PART_OFF);
  unsigned* list = (unsigned*)(ws + LIST_OFF);
  unsigned* stash = (unsigned*)(ws + STASH_OFF);
  unsigned short* xbf = (unsigned short*)(ws + XBF_OFF);
  unsigned short* cbf = (unsigned short*)(ws + CBF_OFF);
  float* out = (float*)d_out;

  hipMemsetAsync(cells, 0, 262144, stream);
  hipMemsetAsync(cnt, 0, 256, stream);

  if (ws_size >= (size_t)WS_NEED_FAST) {
    convert_kernel<<<dim3(NCODES + NROWS), 256, 0, stream>>>(emb, x, cbf, xbf, c2, x2);
    score_fast_kernel<<<dim3(NROWS / BM, (QN + BN - 1) / BN, NSEG), 256, 0, stream>>>(
        xbf, cbf, c2, x2, stash);
    filter_kernel<<<dim3(8192), 256, 0, stream>>>(stash, list, cnt);
  } else if (ws_size >= (size_t)WS_NEED_A) {
    rowsq_kernel<<<dim3(NCODES + NROWS), 256, 0, stream>>>(emb, x, c2, x2);
    score_mfma_kernel<1><<<dim3(NROWS / BM, (QN + BN - 1) / BN, NSEG), 256, 0, stream>>>(
        x, emb, c2, x2, minf, stash, list, cnt);
    filter_kernel<<<dim3(8192), 256, 0, stream>>>(stash, list, cnt);
  } else {
    hipMemsetAsync(minf, 0xFF, 131072, stream);
    rowsq_kernel<<<dim3(NCODES + NROWS), 256, 0, stream>>>(emb, x, c2, x2);
    score_mfma_kernel<0><<<dim3(NROWS / BM, (QN + BN - 1) / BN, NSEG), 256, 0, stream>>>(
        x, emb, c2, x2, minf, stash, list, cnt);
    score_mfma_kernel<2><<<dim3(NROWS / BM, (QN + BN - 1) / BN, NSEG), 256, 0, stream>>>(
        x, emb, c2, x2, minf, stash, list, cnt);
  }
  rescore_kernel<<<dim3(1024), 256, 0, stream>>>(x, emb, c2, x2, list, cnt, cells);
  gather_kernel<<<dim3(NROWS), 256, 0, stream>>>(x, emb, mask, cells, out, part);
  finalize_kernel<<<dim3(1), 256, 0, stream>>>(part, out + (size_t)NROWS * D_DIM);
}